// Round 10
// baseline (38.663 us; speedup 1.0000x reference)
//
#include <hip/hip_runtime.h>
#include <math.h>

// h [8,4096,512] f32, patch_ids [8,4096] i32 sorted per batch, P=1024, k=4.
// Out [8,1024,512] f32.
#define BS   8
#define SEQ  4096
#define DIM  512
#define NP   1024
#define KTOP 4
#define NEGINF_C (-1.0e9f)

typedef float f32x4 __attribute__((ext_vector_type(4)));

// ---------------------------------------------------------------------------
// DIAGNOSTIC kernel D: pure streaming in the SAME structure as the real
// kernel (8192 blocks x 128 threads), no search, no ins5, no output logic.
// Block i reads rows [4i, 4i+4) of flattened h [BS*SEQ][DIM]; every lane
// makes 4 independent f32x4 loads, fmax-reduces, writes one f32x4 to d_ws
// (unique slot, all loads live). T_D = dur - 25.2us isolates the streaming
// cost of this block granularity.
// ---------------------------------------------------------------------------
__global__ __launch_bounds__(128) void diag_stream_kernel(const float* __restrict__ h,
                                                          float* __restrict__ ws) {
    const int blk = blockIdx.x;
    const int tid = threadIdx.x;
    const f32x4* hr = (const f32x4*)h + (size_t)blk * 4 * (DIM / 4) + tid;
    const f32x4 v0 = hr[0 * (DIM / 4)];
    const f32x4 v1 = hr[1 * (DIM / 4)];
    const f32x4 v2 = hr[2 * (DIM / 4)];
    const f32x4 v3 = hr[3 * (DIM / 4)];
    f32x4 r;
    r.x = fmaxf(fmaxf(v0.x, v1.x), fmaxf(v2.x, v3.x));
    r.y = fmaxf(fmaxf(v0.y, v1.y), fmaxf(v2.y, v3.y));
    r.z = fmaxf(fmaxf(v0.z, v1.z), fmaxf(v2.z, v3.z));
    r.w = fmaxf(fmaxf(v0.w, v1.w), fmaxf(v2.w, v3.w));
    ((f32x4*)ws)[(size_t)blk * 128 + tid] = r;
}

// ---------------------------------------------------------------------------
// Real kernel: EXACT copy of R9 (passed, absmax 0.0, 25.2us).
// ---------------------------------------------------------------------------
__device__ __forceinline__ void ins5(float v, float& m0, float& m1, float& m2,
                                     float& m3, float& m4) {
    float a;
    a = fmaxf(m0, v); v = fminf(m0, v); m0 = a;
    a = fmaxf(m1, v); v = fminf(m1, v); m1 = a;
    a = fmaxf(m2, v); v = fminf(m2, v); m2 = a;
    a = fmaxf(m3, v); v = fminf(m3, v); m3 = a;
    m4 = fmaxf(m4, v);
}

#define INS5V(v)                                   \
    do {                                           \
        ins5((v).x, a0, a1, a2, a3, a4);           \
        ins5((v).y, b0, b1, b2, b3, b4);           \
        ins5((v).z, c0, c1, c2, c3, c4);           \
        ins5((v).w, d0, d1, d2, d3, d4);           \
    } while (0)

__device__ __forceinline__ float dedup_avg(float s0, float s1, float s2, float s3,
                                           float s4, int n, float inv_n) {
    const bool e1 = (s1 == s0) & (s1 != -INFINITY);
    const bool e2 = (s2 == s1) & (s2 != -INFINITY);
    const bool e3 = (s3 == s2) & (s3 != -INFINITY);
    const float o1 = e1 ? s2 : s1;
    const float o2 = (e1 | e2) ? s3 : s2;
    const float o3 = (e1 | e2 | e3) ? s4 : s3;
    float acc = (s0 == -INFINITY) ? NEGINF_C : s0;          // n >= 1 here
    if (n > 1) acc += (o1 == -INFINITY) ? NEGINF_C : o1;
    if (n > 2) acc += (o2 == -INFINITY) ? NEGINF_C : o2;
    if (n > 3) acc += (o3 == -INFINITY) ? NEGINF_C : o3;
    return acc * inv_n;
}

__global__ __launch_bounds__(128) void topk_pool_kernel(const float* __restrict__ h,
                                                        const int* __restrict__ pid,
                                                        float* __restrict__ out) {
    const int bp = blockIdx.x;            // b*NP + p
    const int b  = bp >> 10;              // / NP
    const int p  = bp & (NP - 1);
    const int tid = threadIdx.x;

    const int* ids = pid + b * SEQ;
    const int target = p + (tid & 1);
    int lo = 0, hi = SEQ;
    #pragma unroll
    for (int s = 0; s < 13; ++s) {        // ceil(log2(4097)) = 13
        const int mid  = (lo + hi) >> 1;
        const int midc = (mid < SEQ) ? mid : (SEQ - 1);
        const bool go  = (ids[midc] < target) & (mid < hi);
        lo = go ? mid + 1 : lo;
        hi = go ? hi : mid;
    }
    const int start = __shfl(lo, 0);      // lower_bound(p)
    const int end   = __shfl(lo, 1);      // lower_bound(p+1)
    const int cnt   = end - start;

    f32x4* outv = (f32x4*)(out + ((size_t)b * NP + p) * DIM);

    if (cnt == 0) {                       // empty patch -> zero row
        __builtin_nontemporal_store((f32x4){0.f, 0.f, 0.f, 0.f}, &outv[tid]);
        return;
    }

    const f32x4* hr = (const f32x4*)(h + (size_t)b * SEQ * DIM)
                      + (size_t)start * (DIM / 4) + tid;

    float a0 = -INFINITY, a1 = -INFINITY, a2 = -INFINITY, a3 = -INFINITY, a4 = -INFINITY;
    float b0 = -INFINITY, b1 = -INFINITY, b2 = -INFINITY, b3 = -INFINITY, b4 = -INFINITY;
    float c0 = -INFINITY, c1 = -INFINITY, c2 = -INFINITY, c3 = -INFINITY, c4 = -INFINITY;
    float d0 = -INFINITY, d1 = -INFINITY, d2 = -INFINITY, d3 = -INFINITY, d4 = -INFINITY;

    int rem = cnt;
    int off = 0;
    for (; rem >= 4; rem -= 4, off += 4 * (DIM / 4)) {
        const f32x4 v0 = hr[off];
        const f32x4 v1 = hr[off + 1 * (DIM / 4)];
        const f32x4 v2 = hr[off + 2 * (DIM / 4)];
        const f32x4 v3 = hr[off + 3 * (DIM / 4)];
        INS5V(v0);
        INS5V(v1);
        INS5V(v2);
        INS5V(v3);
    }
    for (; rem > 0; --rem, off += (DIM / 4)) {   // exact tail, 0-3 iters, uniform
        const f32x4 v = hr[off];
        INS5V(v);
    }

    const int n = (cnt < KTOP) ? cnt : KTOP;
    const float inv_n = 1.0f / (float)n;
    f32x4 r;
    r.x = dedup_avg(a0, a1, a2, a3, a4, n, inv_n);
    r.y = dedup_avg(b0, b1, b2, b3, b4, n, inv_n);
    r.z = dedup_avg(c0, c1, c2, c3, c4, n, inv_n);
    r.w = dedup_avg(d0, d1, d2, d3, d4, n, inv_n);
    __builtin_nontemporal_store(r, &outv[tid]);
}

// ---------------------------------------------------------------------------
// DIAGNOSTIC ROUND: graph = diag_stream (same structure, pure loads, -> d_ws)
// then the exact R9 kernel (-> d_out, validated). T_D = dur_us - 25.2.
// ---------------------------------------------------------------------------
extern "C" void kernel_launch(void* const* d_in, const int* in_sizes, int n_in,
                              void* d_out, int out_size, void* d_ws, size_t ws_size,
                              hipStream_t stream) {
    const float* h   = (const float*)d_in[0];
    const int*   pid = (const int*)d_in[1];
    float*       out = (float*)d_out;

    if (ws_size >= (size_t)BS * SEQ * DIM * sizeof(float)) {   // 16.8 MB needed
        diag_stream_kernel<<<dim3(BS * SEQ / 4), dim3(128), 0, stream>>>(h, (float*)d_ws);
    }
    topk_pool_kernel<<<dim3(BS * NP), dim3(128), 0, stream>>>(h, pid, out);
}

// Round 11
// 26.870 us; speedup vs baseline: 1.4389x; 1.4389x over previous
//
#include <hip/hip_runtime.h>
#include <math.h>

// h [8,4096,512] f32, patch_ids [8,4096] i32 sorted per batch, P=1024, k=4.
// Out [8,1024,512] f32.
#define BS   8
#define SEQ  4096
#define DIM  512
#define NP   1024
#define KTOP 4
#define NEGINF_C (-1.0e9f)

typedef float f32x4 __attribute__((ext_vector_type(4)));

// ---------------------------------------------------------------------------
// Kernel A (R1-proven): starts[b*(NP+1)+p] = lower_bound(ids[b], p); [NP]=SEQ.
// Trivial (~1-2us). Removes the 13-step dependent search from every pool block.
// ---------------------------------------------------------------------------
__global__ __launch_bounds__(256) void boundaries_kernel(const int* __restrict__ pid,
                                                         int* __restrict__ starts) {
    const int gt = blockIdx.x * 256 + threadIdx.x;   // [0, BS*SEQ)
    const int b  = gt / SEQ;
    const int t  = gt - b * SEQ;
    const int* ids = pid + b * SEQ;
    int* st = starts + b * (NP + 1);

    const int cur  = ids[t];
    const int prev = (t > 0) ? ids[t - 1] : -1;
    for (int p = prev + 1; p <= cur; ++p) st[p] = t;
    if (t == SEQ - 1) {
        for (int p = cur + 1; p <= NP; ++p) st[p] = SEQ;
    }
}

// ---------------------------------------------------------------------------
// 9-op insertion into descending 5-list (multiset top-5). Dup handling is a
// once-per-patch epilogue dedup (exact: R9 absmax 0.0). Masked lanes inject
// -INF which never displaces and is excluded from dedup -> clamped tail loads
// are safe.
// ---------------------------------------------------------------------------
__device__ __forceinline__ void ins5(float v, float& m0, float& m1, float& m2,
                                     float& m3, float& m4) {
    float a;
    a = fmaxf(m0, v); v = fminf(m0, v); m0 = a;
    a = fmaxf(m1, v); v = fminf(m1, v); m1 = a;
    a = fmaxf(m2, v); v = fminf(m2, v); m2 = a;
    a = fmaxf(m3, v); v = fminf(m3, v); m3 = a;
    m4 = fmaxf(m4, v);
}

#define INS5V(v)                                   \
    do {                                           \
        ins5((v).x, a0, a1, a2, a3, a4);           \
        ins5((v).y, b0, b1, b2, b3, b4);           \
        ins5((v).z, c0, c1, c2, c3, c4);           \
        ins5((v).w, d0, d1, d2, d3, d4);           \
    } while (0)

__device__ __forceinline__ float dedup_avg(float s0, float s1, float s2, float s3,
                                           float s4, int n, float inv_n) {
    const bool e1 = (s1 == s0) & (s1 != -INFINITY);
    const bool e2 = (s2 == s1) & (s2 != -INFINITY);
    const bool e3 = (s3 == s2) & (s3 != -INFINITY);
    const float o1 = e1 ? s2 : s1;
    const float o2 = (e1 | e2) ? s3 : s2;
    const float o3 = (e1 | e2 | e3) ? s4 : s3;
    float acc = (s0 == -INFINITY) ? NEGINF_C : s0;          // n >= 1 here
    if (n > 1) acc += (o1 == -INFINITY) ? NEGINF_C : o1;
    if (n > 2) acc += (o2 == -INFINITY) ? NEGINF_C : o2;
    if (n > 3) acc += (o3 == -INFINITY) ? NEGINF_C : o3;
    return acc * inv_n;
}

// ---------------------------------------------------------------------------
// Pool kernel: one block per (b,p), 128 threads x f32x4 = 512 dims.
// Prologue = 2 uniform scalar loads (starts). Unified masked chunk-8 loop:
// 8 clamped loads in flight, out-of-range values masked to -INF; most
// patches (cnt<=8) finish in one straight-line iteration.
// ---------------------------------------------------------------------------
__global__ __launch_bounds__(128) void topk_pool_kernel(const float* __restrict__ h,
                                                        const int* __restrict__ starts,
                                                        float* __restrict__ out) {
    const int bp = blockIdx.x;            // b*NP + p
    const int b  = bp >> 10;              // / NP
    const int p  = bp & (NP - 1);
    const int tid = threadIdx.x;

    const int* st   = starts + b * (NP + 1);
    const int start = st[p];
    const int end   = st[p + 1];
    const int cnt   = end - start;

    f32x4* outv = (f32x4*)(out + ((size_t)b * NP + p) * DIM);

    if (cnt == 0) {                       // empty patch -> zero row
        __builtin_nontemporal_store((f32x4){0.f, 0.f, 0.f, 0.f}, &outv[tid]);
        return;
    }

    const f32x4* hr = (const f32x4*)(h + (size_t)b * SEQ * DIM)
                      + (size_t)start * (DIM / 4) + tid;

    float a0 = -INFINITY, a1 = -INFINITY, a2 = -INFINITY, a3 = -INFINITY, a4 = -INFINITY;
    float b0 = -INFINITY, b1 = -INFINITY, b2 = -INFINITY, b3 = -INFINITY, b4 = -INFINITY;
    float c0 = -INFINITY, c1 = -INFINITY, c2 = -INFINITY, c3 = -INFINITY, c4 = -INFINITY;
    float d0 = -INFINITY, d1 = -INFINITY, d2 = -INFINITY, d3 = -INFINITY, d4 = -INFINITY;

    const int lastoff = (cnt - 1) * (DIM / 4);
    for (int t = 0; t < cnt; t += 8) {
        const int base = t * (DIM / 4);
        f32x4 v[8];
        #pragma unroll
        for (int i = 0; i < 8; ++i) {
            const int o  = base + i * (DIM / 4);
            const int oc = (o < lastoff) ? o : lastoff;      // clamped address
            v[i] = hr[oc];
        }
        #pragma unroll
        for (int i = 0; i < 8; ++i) {
            if (t + i >= cnt) {                              // mask tail -> -INF
                v[i].x = -INFINITY; v[i].y = -INFINITY;
                v[i].z = -INFINITY; v[i].w = -INFINITY;
            }
            INS5V(v[i]);
        }
    }

    const int n = (cnt < KTOP) ? cnt : KTOP;
    const float inv_n = 1.0f / (float)n;
    f32x4 r;
    r.x = dedup_avg(a0, a1, a2, a3, a4, n, inv_n);
    r.y = dedup_avg(b0, b1, b2, b3, b4, n, inv_n);
    r.z = dedup_avg(c0, c1, c2, c3, c4, n, inv_n);
    r.w = dedup_avg(d0, d1, d2, d3, d4, n, inv_n);
    __builtin_nontemporal_store(r, &outv[tid]);
}

// ---------------------------------------------------------------------------
extern "C" void kernel_launch(void* const* d_in, const int* in_sizes, int n_in,
                              void* d_out, int out_size, void* d_ws, size_t ws_size,
                              hipStream_t stream) {
    const float* h   = (const float*)d_in[0];
    const int*   pid = (const int*)d_in[1];
    float*       out = (float*)d_out;
    int*         starts = (int*)d_ws;     // BS*(NP+1)*4 = 32.8 KB

    boundaries_kernel<<<dim3((BS * SEQ) / 256), dim3(256), 0, stream>>>(pid, starts);
    topk_pool_kernel<<<dim3(BS * NP), dim3(128), 0, stream>>>(h, starts, out);
}